// Round 1
// baseline (383.959 us; speedup 1.0000x reference)
//
#include <hip/hip_runtime.h>

#define NN 50000
#define NE 800000
#define DD 128

// ---------------- CSR build ----------------

__global__ void zero_i32(int* __restrict__ p, int n) {
  int i = blockIdx.x * blockDim.x + threadIdx.x;
  if (i < n) p[i] = 0;
}

__global__ void deg_kernel(const int* __restrict__ dst, int* __restrict__ deg) {
  int e = blockIdx.x * blockDim.x + threadIdx.x;
  if (e < NE) atomicAdd(&deg[dst[e]], 1);
}

__global__ __launch_bounds__(1024) void scan_kernel(const int* __restrict__ deg,
                                                    int* __restrict__ rowptr,
                                                    int* __restrict__ cursor) {
  __shared__ int wsum[16];
  __shared__ int carry_s;
  const int tid = threadIdx.x;
  const int lane = tid & 63;
  const int wid = tid >> 6;
  if (tid == 0) carry_s = 0;
  __syncthreads();
  for (int base = 0; base < NN; base += 1024) {
    int i = base + tid;
    int v = (i < NN) ? deg[i] : 0;
    int s = v;
    #pragma unroll
    for (int off = 1; off < 64; off <<= 1) {
      int t = __shfl_up(s, off);
      if (lane >= off) s += t;
    }
    if (lane == 63) wsum[wid] = s;
    __syncthreads();
    if (tid < 16) {
      int ws = wsum[tid];
      #pragma unroll
      for (int off = 1; off < 16; off <<= 1) {
        int t = __shfl_up(ws, off);
        if (tid >= off) ws += t;
      }
      wsum[tid] = ws;  // inclusive scan of wave sums
    }
    __syncthreads();
    int carry = carry_s;
    int excl = carry + (wid ? wsum[wid - 1] : 0) + s - v;
    if (i < NN) { rowptr[i] = excl; cursor[i] = excl; }
    __syncthreads();
    if (tid == 0) carry_s = carry + wsum[15];
  }
  __syncthreads();
  if (tid == 0) rowptr[NN] = carry_s;
}

__global__ void fill_kernel(const int* __restrict__ src, const int* __restrict__ dst,
                            int* __restrict__ cursor, int* __restrict__ col) {
  int e = blockIdx.x * blockDim.x + threadIdx.x;
  if (e < NE) {
    int pos = atomicAdd(&cursor[dst[e]], 1);
    col[pos] = src[e];
  }
}

// ---------------- mean aggregation: one wave per node ----------------

__global__ __launch_bounds__(256) void agg_kernel(const float* __restrict__ h,
                                                  const int* __restrict__ rowptr,
                                                  const int* __restrict__ col,
                                                  float* __restrict__ agg) {
  int node = blockIdx.x * 4 + (threadIdx.x >> 6);
  if (node >= NN) return;
  int lane = threadIdx.x & 63;
  int beg = rowptr[node], end = rowptr[node + 1];
  float ax = 0.f, ay = 0.f;
  int e = beg;
  for (; e + 4 <= end; e += 4) {
    int s0 = col[e], s1 = col[e + 1], s2 = col[e + 2], s3 = col[e + 3];
    float2 v0 = *(const float2*)(h + (size_t)s0 * DD + lane * 2);
    float2 v1 = *(const float2*)(h + (size_t)s1 * DD + lane * 2);
    float2 v2 = *(const float2*)(h + (size_t)s2 * DD + lane * 2);
    float2 v3 = *(const float2*)(h + (size_t)s3 * DD + lane * 2);
    ax += v0.x + v1.x + v2.x + v3.x;
    ay += v0.y + v1.y + v2.y + v3.y;
  }
  for (; e < end; ++e) {
    float2 v = *(const float2*)(h + (size_t)col[e] * DD + lane * 2);
    ax += v.x; ay += v.y;
  }
  float inv = 1.0f / fmaxf((float)(end - beg), 1.0f);
  float2 o; o.x = ax * inv; o.y = ay * inv;
  *(float2*)(agg + (size_t)node * DD + lane * 2) = o;
}

// ---------------- fused linear layer ----------------
// out_row = relu(agg @ Wl^T + bl + h @ Wr^T); layer2 additionally does
// score = ((out_row + x_row) . Ws) + bs; out = a*rr + (1-a)*score.
// Block: 256 threads, 32 nodes. z = [agg | h] (K=256), W' = [Wl | Wr].

template <bool SCORE>
__global__ __launch_bounds__(256) void linear_kernel(
    const float* __restrict__ aggsrc, const float* __restrict__ hsrc,
    const float* __restrict__ Wl, const float* __restrict__ bl,
    const float* __restrict__ Wr,
    float* __restrict__ hout,
    const float* __restrict__ x, const float* __restrict__ rr,
    const float* __restrict__ Wsc, const float* __restrict__ bsp,
    const float* __restrict__ alphap,
    float* __restrict__ out) {
  __shared__ float zbuf[32 * 260];   // 32 nodes x 256 k, row stride 260 (16B aligned)
  __shared__ float wbuf[32 * 132];   // per-K-tile: 32 k x 128 o, stride 132

  const int t = threadIdx.x;
  const int node0 = blockIdx.x * 32;

  // stage z = [agg | h] for 32 nodes (coalesced float4, one row per wave)
  #pragma unroll
  for (int q = 0; q < 8; ++q) {
    int idx = q * 256 + t;
    int nl = idx >> 6;       // node local 0..31
    int k4 = idx & 63;       // float4 index within 256-float row
    int node = node0 + nl; if (node >= NN) node = NN - 1;
    float4 v;
    if (k4 < 32) v = *(const float4*)(aggsrc + (size_t)node * DD + k4 * 4);
    else         v = *(const float4*)(hsrc   + (size_t)node * DD + (k4 - 32) * 4);
    *(float4*)(&zbuf[nl * 260 + k4 * 4]) = v;
  }

  const int tn = t & 31;   // output group: o = tn*4 .. tn*4+3
  const int tm = t >> 5;   // node group:   i = tm*4 .. tm*4+3
  float acc[4][4];
  #pragma unroll
  for (int i = 0; i < 4; ++i)
    #pragma unroll
    for (int j = 0; j < 4; ++j) acc[i][j] = 0.f;

  for (int kt = 0; kt < 8; ++kt) {
    __syncthreads();
    // stage W'[o][kt*32..+31] transposed -> wbuf[k][o]
    #pragma unroll
    for (int q = 0; q < 4; ++q) {
      int idx = q * 256 + t;
      int o = idx >> 3;
      int k4 = idx & 7;
      int kglob = kt * 32 + k4 * 4;
      const float* wsrc = (kglob < DD) ? (Wl + o * DD + kglob)
                                       : (Wr + o * DD + (kglob - DD));
      float4 v = *(const float4*)wsrc;
      wbuf[(k4 * 4 + 0) * 132 + o] = v.x;
      wbuf[(k4 * 4 + 1) * 132 + o] = v.y;
      wbuf[(k4 * 4 + 2) * 132 + o] = v.z;
      wbuf[(k4 * 4 + 3) * 132 + o] = v.w;
    }
    __syncthreads();
    #pragma unroll
    for (int k4 = 0; k4 < 8; ++k4) {
      float4 zv[4];
      #pragma unroll
      for (int i = 0; i < 4; ++i)
        zv[i] = *(const float4*)(&zbuf[(tm * 4 + i) * 260 + kt * 32 + k4 * 4]);
      #pragma unroll
      for (int u = 0; u < 4; ++u) {
        float4 wv = *(const float4*)(&wbuf[(k4 * 4 + u) * 132 + tn * 4]);
        #pragma unroll
        for (int i = 0; i < 4; ++i) {
          float zz = (u == 0) ? zv[i].x : (u == 1) ? zv[i].y
                   : (u == 2) ? zv[i].z : zv[i].w;
          acc[i][0] = fmaf(zz, wv.x, acc[i][0]);
          acc[i][1] = fmaf(zz, wv.y, acc[i][1]);
          acc[i][2] = fmaf(zz, wv.z, acc[i][2]);
          acc[i][3] = fmaf(zz, wv.w, acc[i][3]);
        }
      }
    }
  }

  float blv[4];
  #pragma unroll
  for (int j = 0; j < 4; ++j) blv[j] = bl[tn * 4 + j];

  if (!SCORE) {
    #pragma unroll
    for (int i = 0; i < 4; ++i) {
      int node = node0 + tm * 4 + i;
      if (node < NN) {
        float4 r;
        r.x = fmaxf(acc[i][0] + blv[0], 0.f);
        r.y = fmaxf(acc[i][1] + blv[1], 0.f);
        r.z = fmaxf(acc[i][2] + blv[2], 0.f);
        r.w = fmaxf(acc[i][3] + blv[3], 0.f);
        *(float4*)(hout + (size_t)node * DD + tn * 4) = r;
      }
    }
  } else {
    float wsv[4];
    #pragma unroll
    for (int j = 0; j < 4; ++j) wsv[j] = Wsc[tn * 4 + j];
    float a = 1.f / (1.f + expf(-alphap[0]));
    float bsv = bsp[0];
    #pragma unroll
    for (int i = 0; i < 4; ++i) {
      int node = node0 + tm * 4 + i;
      int nc = node < NN ? node : NN - 1;
      float4 xv = *(const float4*)(x + (size_t)nc * DD + tn * 4);
      float p = 0.f;
      p += (fmaxf(acc[i][0] + blv[0], 0.f) + xv.x) * wsv[0];
      p += (fmaxf(acc[i][1] + blv[1], 0.f) + xv.y) * wsv[1];
      p += (fmaxf(acc[i][2] + blv[2], 0.f) + xv.z) * wsv[2];
      p += (fmaxf(acc[i][3] + blv[3], 0.f) + xv.w) * wsv[3];
      #pragma unroll
      for (int m = 1; m < 32; m <<= 1) p += __shfl_xor(p, m);
      if (tn == 0 && node < NN) {
        out[node] = a * rr[node] + (1.f - a) * (p + bsv);
      }
    }
  }
}

// ---------------- launch ----------------

extern "C" void kernel_launch(void* const* d_in, const int* in_sizes, int n_in,
                              void* d_out, int out_size, void* d_ws, size_t ws_size,
                              hipStream_t stream) {
  const float* x   = (const float*)d_in[0];
  const int*   ei  = (const int*)d_in[1];
  const float* rr  = (const float*)d_in[2];
  const float* Wl1 = (const float*)d_in[3];
  const float* bl1 = (const float*)d_in[4];
  const float* Wr1 = (const float*)d_in[5];
  const float* Wl2 = (const float*)d_in[6];
  const float* bl2 = (const float*)d_in[7];
  const float* Wr2 = (const float*)d_in[8];
  const float* Wsc = (const float*)d_in[9];
  const float* bs  = (const float*)d_in[10];
  const float* al  = (const float*)d_in[11];
  const int* srcv = ei;
  const int* dstv = ei + NE;
  float* out = (float*)d_out;

  size_t off = 0;
  auto nxt = [&](size_t bytes) {
    size_t cur = off; off += (bytes + 255) & ~(size_t)255; return cur;
  };
  int*   deg    = (int*)((char*)d_ws + nxt((size_t)NN * 4));
  int*   rowptr = (int*)((char*)d_ws + nxt((size_t)(NN + 1) * 4));
  int*   cursor = (int*)((char*)d_ws + nxt((size_t)NN * 4));
  int*   col    = (int*)((char*)d_ws + nxt((size_t)NE * 4));
  float* agg    = (float*)((char*)d_ws + nxt((size_t)NN * DD * 4));
  float* h1     = (float*)((char*)d_ws + nxt((size_t)NN * DD * 4));

  zero_i32<<<(NN + 255) / 256, 256, 0, stream>>>(deg, NN);
  deg_kernel<<<(NE + 255) / 256, 256, 0, stream>>>(dstv, deg);
  scan_kernel<<<1, 1024, 0, stream>>>(deg, rowptr, cursor);
  fill_kernel<<<(NE + 255) / 256, 256, 0, stream>>>(srcv, dstv, cursor, col);

  // layer 1
  agg_kernel<<<(NN + 3) / 4, 256, 0, stream>>>(x, rowptr, col, agg);
  linear_kernel<false><<<(NN + 31) / 32, 256, 0, stream>>>(
      agg, x, Wl1, bl1, Wr1, h1, nullptr, nullptr, nullptr, nullptr, nullptr, nullptr);
  // layer 2 (+ residual + score head + blend, fused)
  agg_kernel<<<(NN + 3) / 4, 256, 0, stream>>>(h1, rowptr, col, agg);
  linear_kernel<true><<<(NN + 31) / 32, 256, 0, stream>>>(
      agg, h1, Wl2, bl2, Wr2, nullptr, x, rr, Wsc, bs, al, out);
}

// Round 2
// 248.838 us; speedup vs baseline: 1.5430x; 1.5430x over previous
//
#include <hip/hip_runtime.h>

#define NN 50000
#define NE 800000
#define DD 128

typedef __attribute__((ext_vector_type(8))) short short8v;
typedef __attribute__((ext_vector_type(4))) float float4v;

static __device__ __forceinline__ unsigned short f2b(float f) {
  union { float f; unsigned u; } v; v.f = f;
  unsigned r = v.u + 0x7fff + ((v.u >> 16) & 1);
  return (unsigned short)(r >> 16);
}
static __device__ __forceinline__ float b2f(unsigned short b) {
  union { unsigned u; float f; } v; v.u = ((unsigned)b) << 16;
  return v.f;
}

// ---------------- CSR build ----------------

__global__ void zero_i32(int* __restrict__ p, int n) {
  int i = blockIdx.x * blockDim.x + threadIdx.x;
  if (i < n) p[i] = 0;
}

__global__ void deg_kernel(const int* __restrict__ dst, int* __restrict__ deg) {
  int e = blockIdx.x * blockDim.x + threadIdx.x;
  if (e < NE) atomicAdd(&deg[dst[e]], 1);
}

__global__ __launch_bounds__(1024) void scan_kernel(const int* __restrict__ deg,
                                                    int* __restrict__ rowptr,
                                                    int* __restrict__ cursor) {
  __shared__ int wsum[16];
  __shared__ int carry_s;
  const int tid = threadIdx.x;
  const int lane = tid & 63;
  const int wid = tid >> 6;
  if (tid == 0) carry_s = 0;
  __syncthreads();
  for (int base = 0; base < NN; base += 1024) {
    int i = base + tid;
    int v = (i < NN) ? deg[i] : 0;
    int s = v;
    #pragma unroll
    for (int off = 1; off < 64; off <<= 1) {
      int t = __shfl_up(s, off);
      if (lane >= off) s += t;
    }
    if (lane == 63) wsum[wid] = s;
    __syncthreads();
    if (tid < 16) {
      int ws = wsum[tid];
      #pragma unroll
      for (int off = 1; off < 16; off <<= 1) {
        int t = __shfl_up(ws, off);
        if (tid >= off) ws += t;
      }
      wsum[tid] = ws;
    }
    __syncthreads();
    int carry = carry_s;
    int excl = carry + (wid ? wsum[wid - 1] : 0) + s - v;
    if (i < NN) { rowptr[i] = excl; cursor[i] = excl; }
    __syncthreads();
    if (tid == 0) carry_s = carry + wsum[15];
  }
  __syncthreads();
  if (tid == 0) rowptr[NN] = carry_s;
}

__global__ void fill_kernel(const int* __restrict__ src, const int* __restrict__ dst,
                            int* __restrict__ cursor, int* __restrict__ col) {
  int e = blockIdx.x * blockDim.x + threadIdx.x;
  if (e < NE) {
    int pos = atomicAdd(&cursor[dst[e]], 1);
    col[pos] = src[e];
  }
}

// -------- x -> bf16 convert + fp32 x.Ws dot (for residual score path) --------

__global__ __launch_bounds__(256) void conv_x(const float* __restrict__ x,
                                              const float* __restrict__ Ws,
                                              unsigned short* __restrict__ xb,
                                              float* __restrict__ xw) {
  int node = blockIdx.x * 4 + (threadIdx.x >> 6);
  if (node >= NN) return;
  int lane = threadIdx.x & 63;
  float2 v = *(const float2*)(x + (size_t)node * DD + lane * 2);
  ushort2 o; o.x = f2b(v.x); o.y = f2b(v.y);
  *(ushort2*)(xb + (size_t)node * DD + lane * 2) = o;
  float p = v.x * Ws[lane * 2] + v.y * Ws[lane * 2 + 1];
  #pragma unroll
  for (int m = 1; m < 64; m <<= 1) p += __shfl_xor(p, m);
  if (lane == 0) xw[node] = p;
}

// -------- weight prep: Wcat = [Wl | Wr] as bf16 [128][256] --------

__global__ __launch_bounds__(256) void prep_w(const float* __restrict__ Wl1,
                                              const float* __restrict__ Wr1,
                                              const float* __restrict__ Wl2,
                                              const float* __restrict__ Wr2,
                                              unsigned short* __restrict__ W1,
                                              unsigned short* __restrict__ W2) {
  int idx = blockIdx.x * 256 + threadIdx.x;  // 2 * 128 * 256 = 65536
  int half = idx >> 15;
  int i = idx & 32767;
  int o = i >> 8;
  int k = i & 255;
  const float* Wl = half ? Wl2 : Wl1;
  const float* Wr = half ? Wr2 : Wr1;
  float v = (k < DD) ? Wl[o * DD + k] : Wr[o * DD + (k - DD)];
  (half ? W2 : W1)[i] = f2b(v);
}

// ---------------- mean aggregation (bf16 in/out, fp32 accum) ----------------

__global__ __launch_bounds__(256) void agg_bf16(const unsigned short* __restrict__ h,
                                                const int* __restrict__ rowptr,
                                                const int* __restrict__ col,
                                                unsigned short* __restrict__ agg) {
  int node = blockIdx.x * 4 + (threadIdx.x >> 6);
  if (node >= NN) return;
  int lane = threadIdx.x & 63;
  int beg = rowptr[node], end = rowptr[node + 1];
  float ax = 0.f, ay = 0.f;
  int e = beg;
  for (; e + 4 <= end; e += 4) {
    int s0 = col[e], s1 = col[e + 1], s2 = col[e + 2], s3 = col[e + 3];
    ushort2 v0 = *(const ushort2*)(h + (size_t)s0 * DD + lane * 2);
    ushort2 v1 = *(const ushort2*)(h + (size_t)s1 * DD + lane * 2);
    ushort2 v2 = *(const ushort2*)(h + (size_t)s2 * DD + lane * 2);
    ushort2 v3 = *(const ushort2*)(h + (size_t)s3 * DD + lane * 2);
    ax += b2f(v0.x) + b2f(v1.x) + b2f(v2.x) + b2f(v3.x);
    ay += b2f(v0.y) + b2f(v1.y) + b2f(v2.y) + b2f(v3.y);
  }
  for (; e < end; ++e) {
    ushort2 v = *(const ushort2*)(h + (size_t)col[e] * DD + lane * 2);
    ax += b2f(v.x); ay += b2f(v.y);
  }
  float inv = 1.0f / fmaxf((float)(end - beg), 1.0f);
  ushort2 o; o.x = f2b(ax * inv); o.y = f2b(ay * inv);
  *(ushort2*)(agg + (size_t)node * DD + lane * 2) = o;
}

// ---------------- fused MFMA linear layer ----------------
// Tile: 128 nodes x 128 outs, K=256 (z = [agg | h]). 4 waves, each owns 32 outs.
// W fragments kept in registers; z staged reg->LDS with XOR chunk swizzle.

template <bool SCORE>
__global__ __launch_bounds__(256) void linear_mfma(
    const unsigned short* __restrict__ aggb, const unsigned short* __restrict__ hb,
    const unsigned short* __restrict__ Wcat, const float* __restrict__ bl,
    unsigned short* __restrict__ hout,
    const float* __restrict__ Ws, const float* __restrict__ bsp,
    const float* __restrict__ alphap, const float* __restrict__ rr,
    const float* __restrict__ xw, float* __restrict__ out) {
  __shared__ unsigned short zl[128 * 256];  // 64 KiB; rows of 32 16B-chunks, chunk^=(row&7)
  __shared__ float sbuf[128];

  const int t = threadIdx.x;
  const int wid = t >> 6;
  const int l = t & 63;
  const int lg = l >> 4;   // k-group 0..3
  const int lm = l & 15;   // m (A) / n (B) within fragment
  const int node0 = blockIdx.x * 128;
  const int nb = wid * 32;

  // B fragments from global (L2-resident, 64KB reused by all blocks)
  short8v bfr[2][8];
  #pragma unroll
  for (int nf = 0; nf < 2; ++nf)
    #pragma unroll
    for (int kt = 0; kt < 8; ++kt)
      bfr[nf][kt] = *(const short8v*)(Wcat + (size_t)(nb + nf * 16 + lm) * 256 + kt * 32 + lg * 8);

  if (SCORE && t < 128) sbuf[t] = 0.f;

  // stage z = [agg | h] for 128 nodes, 16B/lane/iter, swizzled chunk placement
  #pragma unroll
  for (int q = 0; q < 16; ++q) {
    int idx = q * 256 + t;
    int row = idx >> 5;       // node-local 0..127
    int c = idx & 31;         // global k-chunk (16B = 8 bf16)
    int node = node0 + row; if (node >= NN) node = NN - 1;
    const unsigned short* src = (c < 16)
        ? (aggb + (size_t)node * DD + c * 8)
        : (hb   + (size_t)node * DD + (c - 16) * 8);
    short8v v = *(const short8v*)src;
    int cs = c ^ (row & 7);
    *(short8v*)(&zl[row * 256 + cs * 8]) = v;
  }
  __syncthreads();

  float4v acc[8][2];
  #pragma unroll
  for (int mf = 0; mf < 8; ++mf) {
    acc[mf][0] = (float4v){0.f, 0.f, 0.f, 0.f};
    acc[mf][1] = (float4v){0.f, 0.f, 0.f, 0.f};
  }

  #pragma unroll
  for (int kt = 0; kt < 8; ++kt) {
    short8v afr[8];
    #pragma unroll
    for (int mf = 0; mf < 8; ++mf) {
      int row = mf * 16 + lm;
      int c = (kt * 4 + lg) ^ (row & 7);
      afr[mf] = *(const short8v*)(&zl[row * 256 + c * 8]);
    }
    #pragma unroll
    for (int mf = 0; mf < 8; ++mf) {
      acc[mf][0] = __builtin_amdgcn_mfma_f32_16x16x32_bf16(afr[mf], bfr[0][kt], acc[mf][0], 0, 0, 0);
      acc[mf][1] = __builtin_amdgcn_mfma_f32_16x16x32_bf16(afr[mf], bfr[1][kt], acc[mf][1], 0, 0, 0);
    }
  }

  const float b0 = bl[nb + lm];
  const float b1 = bl[nb + 16 + lm];

  if (!SCORE) {
    #pragma unroll
    for (int mf = 0; mf < 8; ++mf) {
      #pragma unroll
      for (int r = 0; r < 4; ++r) {
        int row = node0 + mf * 16 + lg * 4 + r;
        if (row < NN) {
          hout[(size_t)row * DD + nb + lm]      = f2b(fmaxf(acc[mf][0][r] + b0, 0.f));
          hout[(size_t)row * DD + nb + 16 + lm] = f2b(fmaxf(acc[mf][1][r] + b1, 0.f));
        }
      }
    }
  } else {
    const float w0 = Ws[nb + lm];
    const float w1 = Ws[nb + 16 + lm];
    #pragma unroll
    for (int mf = 0; mf < 8; ++mf) {
      #pragma unroll
      for (int r = 0; r < 4; ++r) {
        float p = fmaxf(acc[mf][0][r] + b0, 0.f) * w0
                + fmaxf(acc[mf][1][r] + b1, 0.f) * w1;
        p += __shfl_xor(p, 1);
        p += __shfl_xor(p, 2);
        p += __shfl_xor(p, 4);
        p += __shfl_xor(p, 8);
        if (lm == 0) atomicAdd(&sbuf[mf * 16 + lg * 4 + r], p);
      }
    }
    __syncthreads();
    if (t < 128) {
      int node = node0 + t;
      if (node < NN) {
        float a = 1.f / (1.f + expf(-alphap[0]));
        float score = sbuf[t] + xw[node] + bsp[0];
        out[node] = a * rr[node] + (1.f - a) * score;
      }
    }
  }
}

// ---------------- launch ----------------

extern "C" void kernel_launch(void* const* d_in, const int* in_sizes, int n_in,
                              void* d_out, int out_size, void* d_ws, size_t ws_size,
                              hipStream_t stream) {
  const float* x   = (const float*)d_in[0];
  const int*   ei  = (const int*)d_in[1];
  const float* rr  = (const float*)d_in[2];
  const float* Wl1 = (const float*)d_in[3];
  const float* bl1 = (const float*)d_in[4];
  const float* Wr1 = (const float*)d_in[5];
  const float* Wl2 = (const float*)d_in[6];
  const float* bl2 = (const float*)d_in[7];
  const float* Wr2 = (const float*)d_in[8];
  const float* Wsc = (const float*)d_in[9];
  const float* bs  = (const float*)d_in[10];
  const float* al  = (const float*)d_in[11];
  const int* srcv = ei;
  const int* dstv = ei + NE;
  float* out = (float*)d_out;

  size_t off = 0;
  auto nxt = [&](size_t bytes) {
    size_t cur = off; off += (bytes + 255) & ~(size_t)255; return cur;
  };
  int*            deg    = (int*)((char*)d_ws + nxt((size_t)NN * 4));
  int*            rowptr = (int*)((char*)d_ws + nxt((size_t)(NN + 1) * 4));
  int*            cursor = (int*)((char*)d_ws + nxt((size_t)NN * 4));
  int*            col    = (int*)((char*)d_ws + nxt((size_t)NE * 4));
  unsigned short* xb     = (unsigned short*)((char*)d_ws + nxt((size_t)NN * DD * 2));
  unsigned short* aggb   = (unsigned short*)((char*)d_ws + nxt((size_t)NN * DD * 2));
  unsigned short* h1b    = (unsigned short*)((char*)d_ws + nxt((size_t)NN * DD * 2));
  unsigned short* W1     = (unsigned short*)((char*)d_ws + nxt((size_t)DD * 256 * 2));
  unsigned short* W2     = (unsigned short*)((char*)d_ws + nxt((size_t)DD * 256 * 2));
  float*          xw     = (float*)((char*)d_ws + nxt((size_t)NN * 4));

  zero_i32<<<(NN + 255) / 256, 256, 0, stream>>>(deg, NN);
  deg_kernel<<<(NE + 255) / 256, 256, 0, stream>>>(dstv, deg);
  scan_kernel<<<1, 1024, 0, stream>>>(deg, rowptr, cursor);
  fill_kernel<<<(NE + 255) / 256, 256, 0, stream>>>(srcv, dstv, cursor, col);

  conv_x<<<(NN + 3) / 4, 256, 0, stream>>>(x, Wsc, xb, xw);
  prep_w<<<256, 256, 0, stream>>>(Wl1, Wr1, Wl2, Wr2, W1, W2);

  // layer 1
  agg_bf16<<<(NN + 3) / 4, 256, 0, stream>>>(xb, rowptr, col, aggb);
  linear_mfma<false><<<(NN + 127) / 128, 256, 0, stream>>>(
      aggb, xb, W1, bl1, h1b, nullptr, nullptr, nullptr, nullptr, nullptr, nullptr);
  // layer 2 (+ residual + score head + blend, fused)
  agg_bf16<<<(NN + 3) / 4, 256, 0, stream>>>(h1b, rowptr, col, aggb);
  linear_mfma<true><<<(NN + 127) / 128, 256, 0, stream>>>(
      aggb, h1b, W2, bl2, nullptr, Wsc, bs, al, rr, xw, out);
}

// Round 3
// 181.520 us; speedup vs baseline: 2.1152x; 1.3709x over previous
//
#include <hip/hip_runtime.h>

#define NN 50000
#define NE 800000
#define DD 128

typedef __attribute__((ext_vector_type(8))) short short8v;
typedef __attribute__((ext_vector_type(4))) float float4v;

static __device__ __forceinline__ unsigned short f2b(float f) {
  union { float f; unsigned u; } v; v.f = f;
  unsigned r = v.u + 0x7fff + ((v.u >> 16) & 1);
  return (unsigned short)(r >> 16);
}
static __device__ __forceinline__ float b2f(unsigned short b) {
  union { unsigned u; float f; } v; v.u = ((unsigned)b) << 16;
  return v.f;
}

// ---------------- linked-list adjacency build ----------------
// head[d] = last edge with dst==d; list[e] = {src(e), previous head}.
// list writes are coalesced by e -> no partial-line scatter amplification.

__global__ __launch_bounds__(256) void build_list(const int* __restrict__ src,
                                                  const int* __restrict__ dst,
                                                  int* __restrict__ head,
                                                  uint2* __restrict__ list) {
  int e = blockIdx.x * 256 + threadIdx.x;
  if (e < NE) {
    int old = atomicExch(&head[dst[e]], e);
    list[e] = make_uint2((unsigned)src[e], (unsigned)old);
  }
}

// -------- x -> bf16 convert + fp32 x.Ws dot (for residual score path) --------

__global__ __launch_bounds__(256) void conv_x(const float* __restrict__ x,
                                              const float* __restrict__ Ws,
                                              unsigned short* __restrict__ xb,
                                              float* __restrict__ xw) {
  int node = blockIdx.x * 4 + (threadIdx.x >> 6);
  if (node >= NN) return;
  int lane = threadIdx.x & 63;
  float2 v = *(const float2*)(x + (size_t)node * DD + lane * 2);
  ushort2 o; o.x = f2b(v.x); o.y = f2b(v.y);
  *(ushort2*)(xb + (size_t)node * DD + lane * 2) = o;
  float p = v.x * Ws[lane * 2] + v.y * Ws[lane * 2 + 1];
  #pragma unroll
  for (int m = 1; m < 64; m <<= 1) p += __shfl_xor(p, m);
  if (lane == 0) xw[node] = p;
}

// -------- weight prep: Wcat = [Wl | Wr] as bf16 [128][256] --------

__global__ __launch_bounds__(256) void prep_w(const float* __restrict__ Wl1,
                                              const float* __restrict__ Wr1,
                                              const float* __restrict__ Wl2,
                                              const float* __restrict__ Wr2,
                                              unsigned short* __restrict__ W1,
                                              unsigned short* __restrict__ W2) {
  int idx = blockIdx.x * 256 + threadIdx.x;  // 2 * 128 * 256 = 65536
  int half = idx >> 15;
  int i = idx & 32767;
  int o = i >> 8;
  int k = i & 255;
  const float* Wl = half ? Wl2 : Wl1;
  const float* Wr = half ? Wr2 : Wr1;
  float v = (k < DD) ? Wl[o * DD + k] : Wr[o * DD + (k - DD)];
  (half ? W2 : W1)[i] = f2b(v);
}

// ---------------- mean aggregation via chain walk ----------------
// 16 lanes per node; lane q owns 16B chunk q of the 256B row. Chain step is
// one broadcast 8B load; row gathers are 16B/lane (4 rows per wave-instr).

__global__ __launch_bounds__(256) void agg_list(const unsigned short* __restrict__ h,
                                                const int* __restrict__ head,
                                                const uint2* __restrict__ list,
                                                unsigned short* __restrict__ agg) {
  int node = (blockIdx.x * 256 + threadIdx.x) >> 4;
  if (node >= NN) return;
  int q = threadIdx.x & 15;
  float acc[8] = {0.f, 0.f, 0.f, 0.f, 0.f, 0.f, 0.f, 0.f};
  int e = head[node];
  int cnt = 0;
  while (e >= 0) {
    uint2 en = list[e];
    short8v v = *(const short8v*)(h + (size_t)en.x * DD + q * 8);
    #pragma unroll
    for (int j = 0; j < 8; ++j) acc[j] += b2f((unsigned short)v[j]);
    ++cnt;
    e = (int)en.y;
  }
  float inv = 1.0f / fmaxf((float)cnt, 1.0f);
  short8v o;
  #pragma unroll
  for (int j = 0; j < 8; ++j) o[j] = (short)f2b(acc[j] * inv);
  *(short8v*)(agg + (size_t)node * DD + q * 8) = o;
}

// ---------------- fused MFMA linear layer ----------------
// Tile: 128 nodes x 128 outs, K=256 (z = [agg | h]). 4 waves, each owns 32 outs.
// W fragments kept in registers; z staged reg->LDS with XOR chunk swizzle.

template <bool SCORE>
__global__ __launch_bounds__(256) void linear_mfma(
    const unsigned short* __restrict__ aggb, const unsigned short* __restrict__ hb,
    const unsigned short* __restrict__ Wcat, const float* __restrict__ bl,
    unsigned short* __restrict__ hout,
    const float* __restrict__ Ws, const float* __restrict__ bsp,
    const float* __restrict__ alphap, const float* __restrict__ rr,
    const float* __restrict__ xw, float* __restrict__ out) {
  __shared__ unsigned short zl[128 * 256];  // 64 KiB; rows of 32 16B-chunks, chunk^=(row&7)
  __shared__ float sbuf[128];

  const int t = threadIdx.x;
  const int wid = t >> 6;
  const int l = t & 63;
  const int lg = l >> 4;   // k-group 0..3
  const int lm = l & 15;   // m (A) / n (B) within fragment
  const int node0 = blockIdx.x * 128;
  const int nb = wid * 32;

  // B fragments from global (L2-resident, 64KB reused by all blocks)
  short8v bfr[2][8];
  #pragma unroll
  for (int nf = 0; nf < 2; ++nf)
    #pragma unroll
    for (int kt = 0; kt < 8; ++kt)
      bfr[nf][kt] = *(const short8v*)(Wcat + (size_t)(nb + nf * 16 + lm) * 256 + kt * 32 + lg * 8);

  if (SCORE && t < 128) sbuf[t] = 0.f;

  // stage z = [agg | h] for 128 nodes, 16B/lane/iter, swizzled chunk placement
  #pragma unroll
  for (int q = 0; q < 16; ++q) {
    int idx = q * 256 + t;
    int row = idx >> 5;       // node-local 0..127
    int c = idx & 31;         // global k-chunk (16B = 8 bf16)
    int node = node0 + row; if (node >= NN) node = NN - 1;
    const unsigned short* src = (c < 16)
        ? (aggb + (size_t)node * DD + c * 8)
        : (hb   + (size_t)node * DD + (c - 16) * 8);
    short8v v = *(const short8v*)src;
    int cs = c ^ (row & 7);
    *(short8v*)(&zl[row * 256 + cs * 8]) = v;
  }
  __syncthreads();

  float4v acc[8][2];
  #pragma unroll
  for (int mf = 0; mf < 8; ++mf) {
    acc[mf][0] = (float4v){0.f, 0.f, 0.f, 0.f};
    acc[mf][1] = (float4v){0.f, 0.f, 0.f, 0.f};
  }

  #pragma unroll
  for (int kt = 0; kt < 8; ++kt) {
    short8v afr[8];
    #pragma unroll
    for (int mf = 0; mf < 8; ++mf) {
      int row = mf * 16 + lm;
      int c = (kt * 4 + lg) ^ (row & 7);
      afr[mf] = *(const short8v*)(&zl[row * 256 + c * 8]);
    }
    #pragma unroll
    for (int mf = 0; mf < 8; ++mf) {
      acc[mf][0] = __builtin_amdgcn_mfma_f32_16x16x32_bf16(afr[mf], bfr[0][kt], acc[mf][0], 0, 0, 0);
      acc[mf][1] = __builtin_amdgcn_mfma_f32_16x16x32_bf16(afr[mf], bfr[1][kt], acc[mf][1], 0, 0, 0);
    }
  }

  const float b0 = bl[nb + lm];
  const float b1 = bl[nb + 16 + lm];

  if (!SCORE) {
    #pragma unroll
    for (int mf = 0; mf < 8; ++mf) {
      #pragma unroll
      for (int r = 0; r < 4; ++r) {
        int row = node0 + mf * 16 + lg * 4 + r;
        if (row < NN) {
          hout[(size_t)row * DD + nb + lm]      = f2b(fmaxf(acc[mf][0][r] + b0, 0.f));
          hout[(size_t)row * DD + nb + 16 + lm] = f2b(fmaxf(acc[mf][1][r] + b1, 0.f));
        }
      }
    }
  } else {
    const float w0 = Ws[nb + lm];
    const float w1 = Ws[nb + 16 + lm];
    #pragma unroll
    for (int mf = 0; mf < 8; ++mf) {
      #pragma unroll
      for (int r = 0; r < 4; ++r) {
        float p = fmaxf(acc[mf][0][r] + b0, 0.f) * w0
                + fmaxf(acc[mf][1][r] + b1, 0.f) * w1;
        p += __shfl_xor(p, 1);
        p += __shfl_xor(p, 2);
        p += __shfl_xor(p, 4);
        p += __shfl_xor(p, 8);
        if (lm == 0) atomicAdd(&sbuf[mf * 16 + lg * 4 + r], p);
      }
    }
    __syncthreads();
    if (t < 128) {
      int node = node0 + t;
      if (node < NN) {
        float a = 1.f / (1.f + expf(-alphap[0]));
        float score = sbuf[t] + xw[node] + bsp[0];
        out[node] = a * rr[node] + (1.f - a) * score;
      }
    }
  }
}

// ---------------- launch ----------------

extern "C" void kernel_launch(void* const* d_in, const int* in_sizes, int n_in,
                              void* d_out, int out_size, void* d_ws, size_t ws_size,
                              hipStream_t stream) {
  const float* x   = (const float*)d_in[0];
  const int*   ei  = (const int*)d_in[1];
  const float* rr  = (const float*)d_in[2];
  const float* Wl1 = (const float*)d_in[3];
  const float* bl1 = (const float*)d_in[4];
  const float* Wr1 = (const float*)d_in[5];
  const float* Wl2 = (const float*)d_in[6];
  const float* bl2 = (const float*)d_in[7];
  const float* Wr2 = (const float*)d_in[8];
  const float* Wsc = (const float*)d_in[9];
  const float* bs  = (const float*)d_in[10];
  const float* al  = (const float*)d_in[11];
  const int* srcv = ei;
  const int* dstv = ei + NE;
  float* out = (float*)d_out;

  size_t off = 0;
  auto nxt = [&](size_t bytes) {
    size_t cur = off; off += (bytes + 255) & ~(size_t)255; return cur;
  };
  int*            head = (int*)((char*)d_ws + nxt((size_t)NN * 4));
  uint2*          list = (uint2*)((char*)d_ws + nxt((size_t)NE * 8));
  unsigned short* xb   = (unsigned short*)((char*)d_ws + nxt((size_t)NN * DD * 2));
  unsigned short* aggb = (unsigned short*)((char*)d_ws + nxt((size_t)NN * DD * 2));
  unsigned short* h1b  = (unsigned short*)((char*)d_ws + nxt((size_t)NN * DD * 2));
  unsigned short* W1   = (unsigned short*)((char*)d_ws + nxt((size_t)DD * 256 * 2));
  unsigned short* W2   = (unsigned short*)((char*)d_ws + nxt((size_t)DD * 256 * 2));
  float*          xw   = (float*)((char*)d_ws + nxt((size_t)NN * 4));

  hipMemsetAsync(head, 0xFF, (size_t)NN * 4, stream);  // head = -1
  build_list<<<(NE + 255) / 256, 256, 0, stream>>>(srcv, dstv, head, list);

  conv_x<<<(NN + 3) / 4, 256, 0, stream>>>(x, Wsc, xb, xw);
  prep_w<<<256, 256, 0, stream>>>(Wl1, Wr1, Wl2, Wr2, W1, W2);

  // layer 1
  agg_list<<<(NN * 16 + 255) / 256, 256, 0, stream>>>(xb, head, list, aggb);
  linear_mfma<false><<<(NN + 127) / 128, 256, 0, stream>>>(
      aggb, xb, W1, bl1, h1b, nullptr, nullptr, nullptr, nullptr, nullptr, nullptr);
  // layer 2 (+ residual + score head + blend, fused)
  agg_list<<<(NN * 16 + 255) / 256, 256, 0, stream>>>(h1b, head, list, aggb);
  linear_mfma<true><<<(NN + 127) / 128, 256, 0, stream>>>(
      aggb, h1b, W2, bl2, nullptr, Wsc, bs, al, rr, xw, out);
}